// Round 3
// baseline (7875.571 us; speedup 1.0000x reference)
//
#include <hip/hip_runtime.h>
#include <stdint.h>

typedef long long ll;
typedef unsigned short u16;

// ---------- edge-index dtype detection (int64 vs int32, decided on device) ----------
__device__ inline bool ei_is64(const void* ei) {
  const int* p = (const int*)ei;
  // int64: p[1],p[3],p[5],p[7] are high words of first 4 indices -> all 0.
  // int32: they are random node ids in [0,100000); all-zero prob ~1e-20.
  return ((p[1] | p[3] | p[5] | p[7]) == 0);
}
__device__ inline int ei_at(const void* ei, ll i, bool is64) {
  return is64 ? (int)((const ll*)ei)[i] : ((const int*)ei)[i];
}

// ---------- helpers ----------
__device__ inline float fast_tanh(float x) {
  x = fminf(15.f, fmaxf(-15.f, x));
  float e2 = __expf(2.f * x);
  return (e2 - 1.f) / (e2 + 1.f);
}
__device__ inline float fast_sigmoid(float x) { return 1.f / (1.f + __expf(-x)); }

__device__ inline float bf2f(u16 u) {
  union { unsigned int i; float f; } v; v.i = ((unsigned int)u) << 16; return v.f;
}
__device__ inline u16 f2bf(float f) {
  union { float f; unsigned int i; } v; v.f = f;
  unsigned int r = v.i + 0x7FFFu + ((v.i >> 16) & 1u);  // RNE
  return (u16)(r >> 16);
}

// ---------- degree pipeline ----------
__global__ void k_init_deg(float* deg, int n) {
  int i = blockIdx.x * blockDim.x + threadIdx.x;
  if (i < n) deg[i] = 1.0f;  // self-loop
}
__global__ void k_edge_deg(const void* __restrict__ ei, ll E, float* deg) {
  ll i = (ll)blockIdx.x * blockDim.x + threadIdx.x;
  if (i >= E) return;
  bool is64 = ei_is64(ei);
  atomicAdd(&deg[ei_at(ei, E + i, is64)], 1.0f);
}
__global__ void k_fin_deg(const float* __restrict__ deg, float* __restrict__ isd,
                          float* __restrict__ invd, int n) {
  int i = blockIdx.x * blockDim.x + threadIdx.x;
  if (i < n) {
    float d = deg[i];
    isd[i] = rsqrtf(d);
    invd[i] = 1.0f / d;
  }
}

// ---------- diag/self-loop term: out[r, 0:F] = in[r*ldin + 0:F] * invd[r]; inits out ----------
__global__ void k_diag(const float* __restrict__ in, int ldin,
                       const float* __restrict__ invd,
                       float4* __restrict__ out, ll total4, int lgF4) {
  ll idx = (ll)blockIdx.x * blockDim.x + threadIdx.x;
  if (idx >= total4) return;
  int r = (int)(idx >> lgF4);
  int c4 = (int)(idx & ((1 << lgF4) - 1));
  float s = invd[r];
  float4 v = *(const float4*)(in + (size_t)r * ldin + c4 * 4);
  v.x *= s; v.y *= s; v.z *= s; v.w *= s;
  out[idx] = v;  // out contiguous [N, F]
}

// ---------- edge scatter-add: out[d, :] += in[s*ldin + 0:F] * isd[s]*isd[d]; F = 4<<lgC ----------
__global__ void k_scatter(const void* __restrict__ ei, ll E,
                          const float* __restrict__ in, int ldin,
                          float* __restrict__ out,
                          const float* __restrict__ isd, int lgC) {
  ll gid = (ll)blockIdx.x * blockDim.x + threadIdx.x;
  ll total = E << lgC;
  if (gid >= total) return;
  bool is64 = ei_is64(ei);
  ll e = gid >> lgC;
  int c = (int)(gid & ((1 << lgC) - 1));
  int s = ei_at(ei, e, is64);
  int d = ei_at(ei, E + e, is64);
  float nrm = isd[s] * isd[d];
  float4 v = *(const float4*)(in + (size_t)s * ldin + c * 4);
  float* o = out + (((size_t)d << lgC) + c) * 4;
  atomicAdd(o + 0, v.x * nrm);
  atomicAdd(o + 1, v.y * nrm);
  atomicAdd(o + 2, v.z * nrm);
  atomicAdd(o + 3, v.w * nrm);
}

// ---------- elementwise: x[r, j] = tanh(x[r, j] + bias[j]); x contiguous [N, F] ----------
__global__ void k_bias_tanh(float4* __restrict__ x, const float* __restrict__ bias,
                            ll total4, int lgF4) {
  ll idx = (ll)blockIdx.x * blockDim.x + threadIdx.x;
  if (idx >= total4) return;
  int c = (int)(idx & ((1 << lgF4) - 1)) * 4;
  float4 v = x[idx];
  v.x = fast_tanh(v.x + bias[c + 0]);
  v.y = fast_tanh(v.y + bias[c + 1]);
  v.z = fast_tanh(v.z + bias[c + 2]);
  v.w = fast_tanh(v.w + bias[c + 3]);
  x[idx] = v;
}

// ---------- tiled GEMM: C[M,N] = op(A[M,K] @ B[K,N] (+C) (+bias epi)) ----------
// ABF:  A is bf16 (else fp32).   CACC: 0 none, 1 read-add fp32 C, 2 read-add bf16 C.
// EPI:  0 none, 1 tanh(v+bias), 2 sigmoid(v+bias).   OBF: store bf16 (else fp32).
template <int ABF, int CACC, int EPI, int OBF>
__global__ __launch_bounds__(256) void k_gemm(const void* __restrict__ Av, int ldA,
                                              const float* __restrict__ B, int ldB,
                                              const float* __restrict__ bias,
                                              void* __restrict__ Cv, int ldC,
                                              int M, int N, int K) {
  const int BM = 128, BN = 64, BK = 16;
  // +4 pad keeps &As[k][ty*8] 16B-aligned for ds_read_b128 (stride 132 floats).
  __shared__ float As[BK][BM + 4];
  __shared__ float Bs[BK][BN];
  const int tid = threadIdx.x;
  const int tx = tid & 15, ty = tid >> 4;
  const int row0 = blockIdx.y * BM, col0 = blockIdx.x * BN;

  float acc[8][4] = {};

  for (int k0 = 0; k0 < K; k0 += BK) {
    if (ABF) {
      // 128x16 bf16 tile: each thread loads 8 bf16 (16B) and converts.
      const u16* A = (const u16*)Av;
      int r = tid >> 1, kk = (tid & 1) * 8;
      int gr = row0 + r;
      if (gr >= M) gr = M - 1;
      uint4 raw = *(const uint4*)(A + (size_t)gr * ldA + k0 + kk);
      unsigned int w[4] = {raw.x, raw.y, raw.z, raw.w};
#pragma unroll
      for (int j = 0; j < 4; ++j) {
        As[kk + 2 * j + 0][r] = bf2f((u16)(w[j] & 0xFFFFu));
        As[kk + 2 * j + 1][r] = bf2f((u16)(w[j] >> 16));
      }
    } else {
      const float* A = (const float*)Av;
#pragma unroll
      for (int l = 0; l < 2; ++l) {
        int f = tid + l * 256;
        int r = f >> 2, kk = (f & 3) * 4;
        int gr = row0 + r;
        if (gr >= M) gr = M - 1;
        const float4 av = *(const float4*)(A + (size_t)gr * ldA + k0 + kk);
        As[kk + 0][r] = av.x;
        As[kk + 1][r] = av.y;
        As[kk + 2][r] = av.z;
        As[kk + 3][r] = av.w;
      }
    }
    {  // B tile 16xBN, guarded for N tails (classifier N=100)
      int kr = tid >> 4, c = (tid & 15) * 4;
      int gc = col0 + c;
      const float* bp = B + (size_t)(k0 + kr) * ldB;
      float4 bv;
      if (gc + 3 < N) {
        bv = *(const float4*)(bp + gc);
      } else {
        bv.x = (gc + 0 < N) ? bp[gc + 0] : 0.f;
        bv.y = (gc + 1 < N) ? bp[gc + 1] : 0.f;
        bv.z = (gc + 2 < N) ? bp[gc + 2] : 0.f;
        bv.w = (gc + 3 < N) ? bp[gc + 3] : 0.f;
      }
      *(float4*)&Bs[kr][c] = bv;
    }
    __syncthreads();
#pragma unroll
    for (int k = 0; k < BK; ++k) {
      float a[8], b[4];
      *(float4*)&a[0] = *(const float4*)&As[k][ty * 8];
      *(float4*)&a[4] = *(const float4*)&As[k][ty * 8 + 4];
      *(float4*)&b[0] = *(const float4*)&Bs[k][tx * 4];
#pragma unroll
      for (int i = 0; i < 8; ++i)
#pragma unroll
        for (int j = 0; j < 4; ++j) acc[i][j] += a[i] * b[j];
    }
    __syncthreads();
  }

#pragma unroll
  for (int i = 0; i < 8; ++i) {
    int gr = row0 + ty * 8 + i;
    if (gr >= M) break;
#pragma unroll
    for (int j = 0; j < 4; ++j) {
      int gc = col0 + tx * 4 + j;
      if (gc >= N) continue;
      float v = acc[i][j];
      size_t off = (size_t)gr * ldC + gc;
      if (CACC == 1) v += ((const float*)Cv)[off];
      if (CACC == 2) v += bf2f(((const u16*)Cv)[off]);
      if (EPI == 1) v = fast_tanh(v + bias[gc]);
      if (EPI == 2) v = fast_sigmoid(v + bias[gc]);
      if (OBF) ((u16*)Cv)[off] = f2bf(v);
      else     ((float*)Cv)[off] = v;
    }
  }
}

// ---------- launch ----------
static inline int cdiv(ll a, ll b) { return (int)((a + b - 1) / b); }

extern "C" void kernel_launch(void* const* d_in, const int* in_sizes, int n_in,
                              void* d_out, int out_size, void* d_ws, size_t ws_size,
                              hipStream_t stream) {
  const float* x  = (const float*)d_in[0];
  const void*  ei = d_in[1];
  const float* W1 = (const float*)d_in[2];
  const float* b1 = (const float*)d_in[3];
  const float* W2 = (const float*)d_in[4];
  const float* b2 = (const float*)d_in[5];
  const float* W3 = (const float*)d_in[6];
  const float* b3 = (const float*)d_in[7];
  const float* Wc = (const float*)d_in[8];
  const float* bc = (const float*)d_in[9];

  const int Nn = in_sizes[0] / 256;  // 100000
  const ll  E  = in_sizes[1] / 2;    // 400000

  // ===== d_ws: only 256.0 MB (244.1 MiB) =====
  //   h1 [N,1024] bf16 (204.8 MB) | q3 [N,128] fp32 (51.2 MB)
  u16*   h1 = (u16*)d_ws;
  float* q3 = (float*)((char*)d_ws + (size_t)Nn * 1024 * 2);

  // ===== d_out doubles as scratch (22.8M floats), fully rewritten before return =====
  //   [0 : 3Nn)          deg | isd | invd      (dead before classifier writes out)
  //   [3Nn : 3Nn+12.8M)  staging stA/stB       (dead before L3 writes hout)
  //   final: out [0 : Nn*100) | hout [Nn*100 : Nn*228)
  float* ob   = (float*)d_out;
  float* deg  = ob;
  float* isd  = ob + Nn;
  float* invd = ob + 2 * (size_t)Nn;
  float* stA  = ob + 3 * (size_t)Nn;              // L1: Sx chunk [N,128]; L2: q_c [N,64]
  float* stB  = stA + (size_t)Nn * 64;            // L2: z_c [N,64]
  float* outf = ob;                               // [N,100] final
  float* hout = ob + (size_t)Nn * 100;            // [N,128] final h3

  const int T = 256;
  const int GY = cdiv(Nn, 128);

  // ---- degrees ----
  k_init_deg<<<cdiv(Nn, T), T, 0, stream>>>(deg, Nn);
  k_edge_deg<<<cdiv(E, T), T, 0, stream>>>(ei, E, deg);
  k_fin_deg<<<cdiv(Nn, T), T, 0, stream>>>(deg, isd, invd, Nn);

  // ---- layer 1: h1 = tanh((S x) @ W1 + b1), K-chunked (2 x 128), bf16 partial RMW ----
  for (int c = 0; c < 2; ++c) {
    const int c0 = c * 128;
    ll t4 = (ll)Nn * 32;
    k_diag<<<cdiv(t4, T), T, 0, stream>>>(x + c0, 256, invd, (float4*)stA, t4, 5);
    k_scatter<<<cdiv(E << 5, T), T, 0, stream>>>(ei, E, x + c0, 256, stA, isd, 5);
    dim3 g(16, GY);
    if (c == 0)
      k_gemm<0, 0, 0, 1><<<g, T, 0, stream>>>(stA, 128, W1 + (size_t)c0 * 1024, 1024,
                                              nullptr, h1, 1024, Nn, 1024, 128);
    else
      k_gemm<0, 2, 1, 1><<<g, T, 0, stream>>>(stA, 128, W1 + (size_t)c0 * 1024, 1024,
                                              b1, h1, 1024, Nn, 1024, 128);
  }

  // ---- layer 2 fused with layer-3 GEMM, col-chunked (8 x 64):
  //      q_c = h1@W2[:,c] ; z_c = S q_c ; h2_c = tanh(z_c + b2_c) ; q3 += h2_c @ W3[c,:] ----
  for (int c = 0; c < 8; ++c) {
    const int c0 = c * 64;
    {
      dim3 g(1, GY);
      k_gemm<1, 0, 0, 0><<<g, T, 0, stream>>>(h1, 1024, W2 + c0, 512,
                                              nullptr, stA, 64, Nn, 64, 1024);
    }
    ll t4 = (ll)Nn * 16;
    k_diag<<<cdiv(t4, T), T, 0, stream>>>(stA, 64, invd, (float4*)stB, t4, 4);
    k_scatter<<<cdiv(E << 4, T), T, 0, stream>>>(ei, E, stA, 64, stB, isd, 4);
    k_bias_tanh<<<cdiv(t4, T), T, 0, stream>>>((float4*)stB, b2 + c0, t4, 4);
    {
      dim3 g(2, GY);
      if (c == 0)
        k_gemm<0, 0, 0, 0><<<g, T, 0, stream>>>(stB, 64, W3 + (size_t)c0 * 128, 128,
                                                nullptr, q3, 128, Nn, 128, 64);
      else
        k_gemm<0, 1, 0, 0><<<g, T, 0, stream>>>(stB, 64, W3 + (size_t)c0 * 128, 128,
                                                nullptr, q3, 128, Nn, 128, 64);
    }
  }

  // ---- layer 3 aggregation: h3 = tanh(S q3 + b3) -> hout (in d_out) ----
  {
    ll t4 = (ll)Nn * 32;
    k_diag<<<cdiv(t4, T), T, 0, stream>>>(q3, 128, invd, (float4*)hout, t4, 5);
    k_scatter<<<cdiv(E << 5, T), T, 0, stream>>>(ei, E, q3, 128, hout, isd, 5);
    k_bias_tanh<<<cdiv(t4, T), T, 0, stream>>>((float4*)hout, b3, t4, 5);
  }

  // ---- classifier: out = sigmoid(h3 @ Wc + bc) ----
  {
    dim3 g(2, GY);
    k_gemm<0, 0, 2, 0><<<g, T, 0, stream>>>(hout, 128, Wc, 100, bc, outf, 100, Nn, 100, 128);
  }
}

// Round 4
// 3830.362 us; speedup vs baseline: 2.0561x; 2.0561x over previous
//
#include <hip/hip_runtime.h>
#include <stdint.h>

typedef long long ll;
typedef unsigned short u16;

// ---------- edge-index dtype detection (int64 vs int32, decided on device) ----------
__device__ inline bool ei_is64(const void* ei) {
  const int* p = (const int*)ei;
  // int64: p[1],p[3],p[5],p[7] are high words of first 4 indices -> all 0.
  // int32: they are random node ids in [0,100000); all-zero prob ~1e-20.
  return ((p[1] | p[3] | p[5] | p[7]) == 0);
}
__device__ inline int ei_at(const void* ei, ll i, bool is64) {
  return is64 ? (int)((const ll*)ei)[i] : ((const int*)ei)[i];
}

// ---------- helpers ----------
__device__ inline float fast_tanh(float x) {
  x = fminf(15.f, fmaxf(-15.f, x));
  float e2 = __expf(2.f * x);
  return (e2 - 1.f) / (e2 + 1.f);
}
__device__ inline float fast_sigmoid(float x) { return 1.f / (1.f + __expf(-x)); }

__device__ inline float bf2f(u16 u) {
  union { unsigned int i; float f; } v; v.i = ((unsigned int)u) << 16; return v.f;
}
__device__ inline u16 f2bf(float f) {
  union { float f; unsigned int i; } v; v.f = f;
  unsigned int r = v.i + 0x7FFFu + ((v.i >> 16) & 1u);  // RNE
  return (u16)(r >> 16);
}

// ---------- degree pipeline ----------
__global__ void k_init(float* deg, int* cursor, int n) {
  int i = blockIdx.x * blockDim.x + threadIdx.x;
  if (i < n) { deg[i] = 1.0f; cursor[i] = 0; }  // self-loop weight 1
}
__global__ void k_edge_deg(const void* __restrict__ ei, ll E, float* deg) {
  ll i = (ll)blockIdx.x * blockDim.x + threadIdx.x;
  if (i >= E) return;
  bool is64 = ei_is64(ei);
  atomicAdd(&deg[ei_at(ei, E + i, is64)], 1.0f);
}
__global__ void k_fin_deg(const float* __restrict__ deg, float* __restrict__ isd,
                          float* __restrict__ invd, int n) {
  int i = blockIdx.x * blockDim.x + threadIdx.x;
  if (i < n) {
    float d = deg[i];
    isd[i] = rsqrtf(d);
    invd[i] = 1.0f / d;
  }
}

// ---------- single-block prefix scan: row_ptr[0]=0; row_ptr[i+1]=sum of in-degrees ----------
__global__ __launch_bounds__(1024) void k_scan(const float* __restrict__ deg,
                                               int* __restrict__ rowp, int n) {
  __shared__ int sm[1024];
  __shared__ int carry;
  const int tid = threadIdx.x;
  if (tid == 0) { carry = 0; rowp[0] = 0; }
  __syncthreads();
  for (int base = 0; base < n; base += 1024) {
    int i = base + tid;
    int v = (i < n) ? ((int)deg[i] - 1) : 0;  // in-degree (deg includes +1 self-loop)
    sm[tid] = v;
    __syncthreads();
#pragma unroll
    for (int off = 1; off < 1024; off <<= 1) {
      int t = (tid >= off) ? sm[tid - off] : 0;
      __syncthreads();
      sm[tid] += t;
      __syncthreads();
    }
    int inc = sm[tid] + carry;  // inclusive prefix
    if (i < n) rowp[i + 1] = inc;
    __syncthreads();
    if (tid == 1023) carry = inc;
    __syncthreads();
  }
}

// ---------- CSR fill: bucket edges by dst ----------
__global__ void k_fill(const void* __restrict__ ei, ll E,
                       const int* __restrict__ rowp, int* __restrict__ cursor,
                       int* __restrict__ col, float* __restrict__ w,
                       const float* __restrict__ isd) {
  ll i = (ll)blockIdx.x * blockDim.x + threadIdx.x;
  if (i >= E) return;
  bool is64 = ei_is64(ei);
  int s = ei_at(ei, i, is64);
  int d = ei_at(ei, E + i, is64);
  int pos = rowp[d] + atomicAdd(&cursor[d], 1);
  col[pos] = s;
  w[pos] = isd[s] * isd[d];
}

// ---------- CSR gather aggregation (no atomics), fused diag + optional bias/tanh ----------
// out[d, 0:F] = act( invd[d]*in[d*ldin + :] + sum_j w_j * in[col_j*ldin + :] + bias )
// F = 4 << lgC.  EPI: 0 none, 1 tanh(v + bias)
template <int EPI>
__global__ void k_gather(const int* __restrict__ rowp, const int* __restrict__ col,
                         const float* __restrict__ w,
                         const float* __restrict__ in, int ldin,
                         const float* __restrict__ invd, const float* __restrict__ bias,
                         float4* __restrict__ out, int n, int lgC) {
  ll gid = (ll)blockIdx.x * blockDim.x + threadIdx.x;
  ll total = (ll)n << lgC;
  if (gid >= total) return;
  int d = (int)(gid >> lgC);
  int c4 = (int)(gid & ((1 << lgC) - 1));
  float4 acc;
  {
    float4 v = *(const float4*)(in + (size_t)d * ldin + c4 * 4);
    float s = invd[d];
    acc.x = v.x * s; acc.y = v.y * s; acc.z = v.z * s; acc.w = v.w * s;
  }
  int b = rowp[d], e = rowp[d + 1];
  for (int j = b; j < e; ++j) {
    int s = col[j];
    float wt = w[j];
    float4 v = *(const float4*)(in + (size_t)s * ldin + c4 * 4);
    acc.x += wt * v.x; acc.y += wt * v.y; acc.z += wt * v.z; acc.w += wt * v.w;
  }
  if (EPI == 1) {
    int c = c4 * 4;
    acc.x = fast_tanh(acc.x + bias[c + 0]);
    acc.y = fast_tanh(acc.y + bias[c + 1]);
    acc.z = fast_tanh(acc.z + bias[c + 2]);
    acc.w = fast_tanh(acc.w + bias[c + 3]);
  }
  out[gid] = acc;
}

// ---------- tiled GEMM: C[M,N] = op(A[M,K] @ B[K,N] (+C) (+bias epi)) ----------
// ABF:  A is bf16 (else fp32).   CACC: 0 none, 1 read-add fp32 C, 2 read-add bf16 C.
// EPI:  0 none, 1 tanh(v+bias), 2 sigmoid(v+bias).   OBF: store bf16 (else fp32).
template <int ABF, int CACC, int EPI, int OBF>
__global__ __launch_bounds__(256) void k_gemm(const void* __restrict__ Av, int ldA,
                                              const float* __restrict__ B, int ldB,
                                              const float* __restrict__ bias,
                                              void* __restrict__ Cv, int ldC,
                                              int M, int N, int K) {
  const int BM = 128, BN = 64, BK = 16;
  // +4 pad keeps &As[k][ty*8] 16B-aligned for ds_read_b128 (stride 132 floats).
  __shared__ float As[BK][BM + 4];
  __shared__ float Bs[BK][BN];
  const int tid = threadIdx.x;
  const int tx = tid & 15, ty = tid >> 4;
  const int row0 = blockIdx.y * BM, col0 = blockIdx.x * BN;

  float acc[8][4] = {};

  for (int k0 = 0; k0 < K; k0 += BK) {
    if (ABF) {
      // 128x16 bf16 tile: each thread loads 8 bf16 (16B) and converts.
      const u16* A = (const u16*)Av;
      int r = tid >> 1, kk = (tid & 1) * 8;
      int gr = row0 + r;
      if (gr >= M) gr = M - 1;
      uint4 raw = *(const uint4*)(A + (size_t)gr * ldA + k0 + kk);
      unsigned int wd[4] = {raw.x, raw.y, raw.z, raw.w};
#pragma unroll
      for (int j = 0; j < 4; ++j) {
        As[kk + 2 * j + 0][r] = bf2f((u16)(wd[j] & 0xFFFFu));
        As[kk + 2 * j + 1][r] = bf2f((u16)(wd[j] >> 16));
      }
    } else {
      const float* A = (const float*)Av;
#pragma unroll
      for (int l = 0; l < 2; ++l) {
        int f = tid + l * 256;
        int r = f >> 2, kk = (f & 3) * 4;
        int gr = row0 + r;
        if (gr >= M) gr = M - 1;
        const float4 av = *(const float4*)(A + (size_t)gr * ldA + k0 + kk);
        As[kk + 0][r] = av.x;
        As[kk + 1][r] = av.y;
        As[kk + 2][r] = av.z;
        As[kk + 3][r] = av.w;
      }
    }
    {  // B tile 16xBN, guarded for N tails (classifier N=100)
      int kr = tid >> 4, c = (tid & 15) * 4;
      int gc = col0 + c;
      const float* bp = B + (size_t)(k0 + kr) * ldB;
      float4 bv;
      if (gc + 3 < N) {
        bv = *(const float4*)(bp + gc);
      } else {
        bv.x = (gc + 0 < N) ? bp[gc + 0] : 0.f;
        bv.y = (gc + 1 < N) ? bp[gc + 1] : 0.f;
        bv.z = (gc + 2 < N) ? bp[gc + 2] : 0.f;
        bv.w = (gc + 3 < N) ? bp[gc + 3] : 0.f;
      }
      *(float4*)&Bs[kr][c] = bv;
    }
    __syncthreads();
#pragma unroll
    for (int k = 0; k < BK; ++k) {
      float a[8], b[4];
      *(float4*)&a[0] = *(const float4*)&As[k][ty * 8];
      *(float4*)&a[4] = *(const float4*)&As[k][ty * 8 + 4];
      *(float4*)&b[0] = *(const float4*)&Bs[k][tx * 4];
#pragma unroll
      for (int i = 0; i < 8; ++i)
#pragma unroll
        for (int j = 0; j < 4; ++j) acc[i][j] += a[i] * b[j];
    }
    __syncthreads();
  }

#pragma unroll
  for (int i = 0; i < 8; ++i) {
    int gr = row0 + ty * 8 + i;
    if (gr >= M) break;
#pragma unroll
    for (int j = 0; j < 4; ++j) {
      int gc = col0 + tx * 4 + j;
      if (gc >= N) continue;
      float v = acc[i][j];
      size_t off = (size_t)gr * ldC + gc;
      if (CACC == 1) v += ((const float*)Cv)[off];
      if (CACC == 2) v += bf2f(((const u16*)Cv)[off]);
      if (EPI == 1) v = fast_tanh(v + bias[gc]);
      if (EPI == 2) v = fast_sigmoid(v + bias[gc]);
      if (OBF) ((u16*)Cv)[off] = f2bf(v);
      else     ((float*)Cv)[off] = v;
    }
  }
}

// ---------- launch ----------
static inline int cdiv(ll a, ll b) { return (int)((a + b - 1) / b); }

extern "C" void kernel_launch(void* const* d_in, const int* in_sizes, int n_in,
                              void* d_out, int out_size, void* d_ws, size_t ws_size,
                              hipStream_t stream) {
  const float* x  = (const float*)d_in[0];
  const void*  ei = d_in[1];
  const float* W1 = (const float*)d_in[2];
  const float* b1 = (const float*)d_in[3];
  const float* W2 = (const float*)d_in[4];
  const float* b2 = (const float*)d_in[5];
  const float* W3 = (const float*)d_in[6];
  const float* b3 = (const float*)d_in[7];
  const float* Wc = (const float*)d_in[8];
  const float* bc = (const float*)d_in[9];

  const int Nn = in_sizes[0] / 256;  // 100000
  const ll  E  = in_sizes[1] / 2;    // 400000

  // ===== d_ws: 256.0 MB (proven OK) =====
  //   h1 [N,1024] bf16 (204.8 MB) | q3 [N,128] fp32 (51.2 MB)
  u16*   h1 = (u16*)d_ws;
  float* q3 = (float*)((char*)d_ws + (size_t)Nn * 1024 * 2);

  // ===== d_out scratch (22.8M floats), liveness-scheduled, fully rewritten before return =====
  // [0,3N)            deg|isd|invd      (dead before classifier writes outf)
  // [300k,1.3M)       CSR: rowp|cursor|col|w   (dead after L3 gather)
  // [1.3M,7.7M)       stA  (L1 Sx-chunk / L2 q-chunk)
  // [7.7M,14.1M)      stB  (L2 z-chunk) — overlaps hout tail; stB dead before L3 gather
  // final: outf [0,10M) | hout [10M,22.8M)
  float* ob    = (float*)d_out;
  float* deg   = ob;
  float* isd   = ob + Nn;
  float* invd  = ob + 2 * (size_t)Nn;
  int*   rowp  = (int*)(ob + 300000);            // N+1 ints
  int*   cursor= (int*)(ob + 400004);            // N ints
  int*   colx  = (int*)(ob + 500008);            // E ints
  float* wgt   = ob + 900008;                    // E floats
  float* stA   = ob + 1300016;                   // 6.4M floats
  float* stB   = ob + 7700016;                   // 6.4M floats
  float* outf  = ob;                             // [N,100]
  float* hout  = ob + (size_t)Nn * 100;          // [N,128]

  const int T = 256;
  const int GY = cdiv(Nn, 128);

  // ---- degrees + CSR build ----
  k_init<<<cdiv(Nn, T), T, 0, stream>>>(deg, cursor, Nn);
  k_edge_deg<<<cdiv(E, T), T, 0, stream>>>(ei, E, deg);
  k_fin_deg<<<cdiv(Nn, T), T, 0, stream>>>(deg, isd, invd, Nn);
  k_scan<<<1, 1024, 0, stream>>>(deg, rowp, Nn);
  k_fill<<<cdiv(E, T), T, 0, stream>>>(ei, E, rowp, cursor, colx, wgt, isd);

  // ---- layer 1: h1 = tanh((S x) @ W1 + b1), K-chunked (2 x 128), bf16 partial RMW ----
  for (int c = 0; c < 2; ++c) {
    const int c0 = c * 128;
    ll t4 = (ll)Nn * 32;
    k_gather<0><<<cdiv(t4, T), T, 0, stream>>>(rowp, colx, wgt, x + c0, 256, invd,
                                               nullptr, (float4*)stA, Nn, 5);
    dim3 g(16, GY);
    if (c == 0)
      k_gemm<0, 0, 0, 1><<<g, T, 0, stream>>>(stA, 128, W1 + (size_t)c0 * 1024, 1024,
                                              nullptr, h1, 1024, Nn, 1024, 128);
    else
      k_gemm<0, 2, 1, 1><<<g, T, 0, stream>>>(stA, 128, W1 + (size_t)c0 * 1024, 1024,
                                              b1, h1, 1024, Nn, 1024, 128);
  }

  // ---- layer 2 fused with layer-3 GEMM, col-chunked (8 x 64):
  //      q_c = h1@W2[:,c] ; h2_c = tanh(S q_c + b2_c) ; q3 += h2_c @ W3[c,:] ----
  for (int c = 0; c < 8; ++c) {
    const int c0 = c * 64;
    {
      dim3 g(1, GY);
      k_gemm<1, 0, 0, 0><<<g, T, 0, stream>>>(h1, 1024, W2 + c0, 512,
                                              nullptr, stA, 64, Nn, 64, 1024);
    }
    ll t4 = (ll)Nn * 16;
    k_gather<1><<<cdiv(t4, T), T, 0, stream>>>(rowp, colx, wgt, stA, 64, invd,
                                               b2 + c0, (float4*)stB, Nn, 4);
    {
      dim3 g(2, GY);
      if (c == 0)
        k_gemm<0, 0, 0, 0><<<g, T, 0, stream>>>(stB, 64, W3 + (size_t)c0 * 128, 128,
                                                nullptr, q3, 128, Nn, 128, 64);
      else
        k_gemm<0, 1, 0, 0><<<g, T, 0, stream>>>(stB, 64, W3 + (size_t)c0 * 128, 128,
                                                nullptr, q3, 128, Nn, 128, 64);
    }
  }

  // ---- layer 3 aggregation: h3 = tanh(S q3 + b3) -> hout ----
  {
    ll t4 = (ll)Nn * 32;
    k_gather<1><<<cdiv(t4, T), T, 0, stream>>>(rowp, colx, wgt, q3, 128, invd,
                                               b3, (float4*)hout, Nn, 5);
  }

  // ---- classifier: out = sigmoid(h3 @ Wc + bc) ----
  {
    dim3 g(2, GY);
    k_gemm<0, 0, 2, 0><<<g, T, 0, stream>>>(hout, 128, Wc, 100, bc, outf, 100, Nn, 100, 128);
  }
}

// Round 5
// 1528.039 us; speedup vs baseline: 5.1540x; 2.5067x over previous
//
#include <hip/hip_runtime.h>
#include <stdint.h>

typedef long long ll;
typedef unsigned short u16;
typedef __attribute__((ext_vector_type(8))) short bf16x8;
typedef __attribute__((ext_vector_type(4))) float f32x4;

// ---------- edge-index dtype detection (int64 vs int32, decided on device) ----------
__device__ inline bool ei_is64(const void* ei) {
  const int* p = (const int*)ei;
  return ((p[1] | p[3] | p[5] | p[7]) == 0);
}
__device__ inline int ei_at(const void* ei, ll i, bool is64) {
  return is64 ? (int)((const ll*)ei)[i] : ((const int*)ei)[i];
}

// ---------- helpers ----------
__device__ inline float fast_tanh(float x) {
  x = fminf(15.f, fmaxf(-15.f, x));
  float e2 = __expf(2.f * x);
  return (e2 - 1.f) / (e2 + 1.f);
}
__device__ inline float fast_sigmoid(float x) { return 1.f / (1.f + __expf(-x)); }

__device__ inline float bf2f(u16 u) {
  union { unsigned int i; float f; } v; v.i = ((unsigned int)u) << 16; return v.f;
}
__device__ inline u16 f2bf(float f) {
  union { float f; unsigned int i; } v; v.f = f;
  unsigned int r = v.i + 0x7FFFu + ((v.i >> 16) & 1u);  // RNE
  return (u16)(r >> 16);
}

// ---------- degree pipeline ----------
__global__ void k_init(float* deg, int* cursor, int n) {
  int i = blockIdx.x * blockDim.x + threadIdx.x;
  if (i < n) { deg[i] = 1.0f; cursor[i] = 0; }
}
__global__ void k_edge_deg(const void* __restrict__ ei, ll E, float* deg) {
  ll i = (ll)blockIdx.x * blockDim.x + threadIdx.x;
  if (i >= E) return;
  bool is64 = ei_is64(ei);
  atomicAdd(&deg[ei_at(ei, E + i, is64)], 1.0f);
}
__global__ void k_fin_deg(const float* __restrict__ deg, float* __restrict__ isd,
                          float* __restrict__ invd, int n) {
  int i = blockIdx.x * blockDim.x + threadIdx.x;
  if (i < n) {
    float d = deg[i];
    isd[i] = rsqrtf(d);
    invd[i] = 1.0f / d;
  }
}

// ---------- 3-kernel prefix scan over in-degrees (98 parallel blocks) ----------
__global__ __launch_bounds__(1024) void k_scan1(const float* __restrict__ deg,
                                                int* __restrict__ rowp,
                                                int* __restrict__ part, int n) {
  __shared__ int sm[1024];
  int b = blockIdx.x, tid = threadIdx.x;
  int i = b * 1024 + tid;
  int v = (i < n) ? ((int)deg[i] - 1) : 0;  // in-degree (deg includes self-loop)
  sm[tid] = v;
  __syncthreads();
  for (int off = 1; off < 1024; off <<= 1) {
    int t = (tid >= off) ? sm[tid - off] : 0;
    __syncthreads();
    sm[tid] += t;
    __syncthreads();
  }
  if (i < n) rowp[i + 1] = sm[tid];
  if (tid == 1023) part[b] = sm[1023];
}
__global__ void k_scan2(const int* __restrict__ part, int* __restrict__ offs, int nb) {
  __shared__ int sm[128];
  int t = threadIdx.x;
  int v = (t < nb) ? part[t] : 0;
  sm[t] = v;
  __syncthreads();
  for (int off = 1; off < 128; off <<= 1) {
    int u = (t >= off) ? sm[t - off] : 0;
    __syncthreads();
    sm[t] += u;
    __syncthreads();
  }
  offs[t] = sm[t] - v;  // exclusive
}
__global__ __launch_bounds__(1024) void k_scan3(int* __restrict__ rowp,
                                                const int* __restrict__ offs, int n) {
  int i = blockIdx.x * 1024 + threadIdx.x;
  if (i == 0) rowp[0] = 0;
  if (i < n) rowp[i + 1] += offs[blockIdx.x];
}

// ---------- CSR fill: bucket edges by dst ----------
__global__ void k_fill(const void* __restrict__ ei, ll E,
                       const int* __restrict__ rowp, int* __restrict__ cursor,
                       int* __restrict__ col, float* __restrict__ w,
                       const float* __restrict__ isd) {
  ll i = (ll)blockIdx.x * blockDim.x + threadIdx.x;
  if (i >= E) return;
  bool is64 = ei_is64(ei);
  int s = ei_at(ei, i, is64);
  int d = ei_at(ei, E + i, is64);
  int pos = rowp[d] + atomicAdd(&cursor[d], 1);
  col[pos] = s;
  w[pos] = isd[s] * isd[d];
}

// ---------- weight transpose + bf16 convert: Wt[n][k] = bf16(W[k][n]) ----------
__global__ void k_wt(const float* __restrict__ W, u16* __restrict__ Wt, int K, int N) {
  int t = blockIdx.x * blockDim.x + threadIdx.x;
  if (t >= K * N) return;
  int k = t % K, n = t / K;
  Wt[t] = f2bf(W[(size_t)k * N + n]);
}

// ---------- CSR gather aggregation, fused diag + optional bias/tanh ----------
// out[d, 0:F] = act( invd[d]*in[d,:] + sum_j w_j * in[col_j,:] + bias ); F = 4<<lgC
// EPI: 0 none, 1 tanh(v+bias).  OBF: 1 -> bf16 out, 0 -> fp32 out.
template <int EPI, int OBF>
__global__ void k_gather(const int* __restrict__ rowp, const int* __restrict__ col,
                         const float* __restrict__ w,
                         const float* __restrict__ in, int ldin,
                         const float* __restrict__ invd, const float* __restrict__ bias,
                         void* __restrict__ outv, int n, int lgC) {
  ll gid = (ll)blockIdx.x * blockDim.x + threadIdx.x;
  ll total = (ll)n << lgC;
  if (gid >= total) return;
  int d = (int)(gid >> lgC);
  int c4 = (int)(gid & ((1 << lgC) - 1));
  float4 acc;
  {
    float4 v = *(const float4*)(in + (size_t)d * ldin + c4 * 4);
    float s = invd[d];
    acc.x = v.x * s; acc.y = v.y * s; acc.z = v.z * s; acc.w = v.w * s;
  }
  int b = rowp[d], e = rowp[d + 1];
  for (int j = b; j < e; ++j) {
    int s = col[j];
    float wt = w[j];
    float4 v = *(const float4*)(in + (size_t)s * ldin + c4 * 4);
    acc.x += wt * v.x; acc.y += wt * v.y; acc.z += wt * v.z; acc.w += wt * v.w;
  }
  if (EPI == 1) {
    int c = c4 * 4;
    acc.x = fast_tanh(acc.x + bias[c + 0]);
    acc.y = fast_tanh(acc.y + bias[c + 1]);
    acc.z = fast_tanh(acc.z + bias[c + 2]);
    acc.w = fast_tanh(acc.w + bias[c + 3]);
  }
  if (OBF) {
    ushort4 o;
    o.x = f2bf(acc.x); o.y = f2bf(acc.y); o.z = f2bf(acc.z); o.w = f2bf(acc.w);
    ((ushort4*)outv)[gid] = o;
  } else {
    ((float4*)outv)[gid] = acc;
  }
}

// ---------- MFMA bf16 GEMM: C[M,Ncols] = A[M,K]bf16 @ Bt[Ncols,K]bf16 ----------
// LDS-free: A frags and Bt frags direct from global (Bt is L2-resident weights).
// Block = 256 thr = 4 waves (2x2), wave tile 64x64 (4x4 frags of 16x16x32).
// CACC: 1 -> C += (fp32 RMW).  EPI: 1 -> tanh(v+bias[gc]).  OBF: 1 -> bf16 store.
// Ncols must be a multiple of 128 (grid.x = Ncols/128).
template <int CACC, int EPI, int OBF>
__global__ __launch_bounds__(256) void k_mfma(const u16* __restrict__ A, int ldA,
                                              const u16* __restrict__ Bt, int ldB,
                                              const float* __restrict__ bias,
                                              void* __restrict__ Cv, int ldC,
                                              int M, int K) {
  const int lane = threadIdx.x & 63;
  const int wid = threadIdx.x >> 6;
  const int wm = wid >> 1, wn = wid & 1;
  const int r0 = blockIdx.y * 128 + wm * 64;
  const int c0 = blockIdx.x * 128 + wn * 64;
  const int lr = lane & 15;        // A: row-in-frag; B: col-in-frag
  const int kb = (lane >> 4) * 8;  // per-lane k offset

  f32x4 acc[4][4];
#pragma unroll
  for (int i = 0; i < 4; ++i)
#pragma unroll
    for (int j = 0; j < 4; ++j) acc[i][j] = (f32x4)0.f;

  const u16* ap[4];
#pragma unroll
  for (int fm = 0; fm < 4; ++fm) {
    int r = r0 + fm * 16 + lr;
    if (r > M - 1) r = M - 1;  // clamp tail rows (stores are guarded)
    ap[fm] = A + (size_t)r * ldA + kb;
  }
  const u16* bp[4];
#pragma unroll
  for (int fn = 0; fn < 4; ++fn) {
    int c = c0 + fn * 16 + lr;
    bp[fn] = Bt + (size_t)c * ldB + kb;
  }

  for (int k0 = 0; k0 < K; k0 += 32) {
    bf16x8 a[4], b[4];
#pragma unroll
    for (int i = 0; i < 4; ++i) a[i] = *(const bf16x8*)(ap[i] + k0);
#pragma unroll
    for (int i = 0; i < 4; ++i) b[i] = *(const bf16x8*)(bp[i] + k0);
#pragma unroll
    for (int fm = 0; fm < 4; ++fm)
#pragma unroll
      for (int fn = 0; fn < 4; ++fn)
        acc[fm][fn] = __builtin_amdgcn_mfma_f32_16x16x32_bf16(a[fm], b[fn], acc[fm][fn], 0, 0, 0);
  }

  // epilogue: C/D mapping col = lane&15, row = (lane>>4)*4 + j (m89-verified)
  const int orow = (lane >> 4) * 4;
  const int ocol = lane & 15;
#pragma unroll
  for (int fm = 0; fm < 4; ++fm) {
#pragma unroll
    for (int j = 0; j < 4; ++j) {
      int gr = r0 + fm * 16 + orow + j;
      if (gr >= M) continue;
#pragma unroll
      for (int fn = 0; fn < 4; ++fn) {
        int gc = c0 + fn * 16 + ocol;
        float v = acc[fm][fn][j];
        size_t off = (size_t)gr * ldC + gc;
        if (CACC) v += ((const float*)Cv)[off];
        if (EPI == 1) v = fast_tanh(v + bias[gc]);
        if (OBF) ((u16*)Cv)[off] = f2bf(v);
        else     ((float*)Cv)[off] = v;
      }
    }
  }
}

// ---------- fp32 VALU GEMM (classifier only: N=100 tail) ----------
template <int ABF, int CACC, int EPI, int OBF>
__global__ __launch_bounds__(256) void k_gemm(const void* __restrict__ Av, int ldA,
                                              const float* __restrict__ B, int ldB,
                                              const float* __restrict__ bias,
                                              void* __restrict__ Cv, int ldC,
                                              int M, int N, int K) {
  const int BM = 128, BN = 64, BK = 16;
  __shared__ float As[BK][BM + 4];
  __shared__ float Bs[BK][BN];
  const int tid = threadIdx.x;
  const int tx = tid & 15, ty = tid >> 4;
  const int row0 = blockIdx.y * BM, col0 = blockIdx.x * BN;

  float acc[8][4] = {};

  for (int k0 = 0; k0 < K; k0 += BK) {
    {
      const float* A = (const float*)Av;
#pragma unroll
      for (int l = 0; l < 2; ++l) {
        int f = tid + l * 256;
        int r = f >> 2, kk = (f & 3) * 4;
        int gr = row0 + r;
        if (gr >= M) gr = M - 1;
        const float4 av = *(const float4*)(A + (size_t)gr * ldA + k0 + kk);
        As[kk + 0][r] = av.x;
        As[kk + 1][r] = av.y;
        As[kk + 2][r] = av.z;
        As[kk + 3][r] = av.w;
      }
    }
    {
      int kr = tid >> 4, c = (tid & 15) * 4;
      int gc = col0 + c;
      const float* bp = B + (size_t)(k0 + kr) * ldB;
      float4 bv;
      if (gc + 3 < N) {
        bv = *(const float4*)(bp + gc);
      } else {
        bv.x = (gc + 0 < N) ? bp[gc + 0] : 0.f;
        bv.y = (gc + 1 < N) ? bp[gc + 1] : 0.f;
        bv.z = (gc + 2 < N) ? bp[gc + 2] : 0.f;
        bv.w = (gc + 3 < N) ? bp[gc + 3] : 0.f;
      }
      *(float4*)&Bs[kr][c] = bv;
    }
    __syncthreads();
#pragma unroll
    for (int k = 0; k < BK; ++k) {
      float a[8], b[4];
      *(float4*)&a[0] = *(const float4*)&As[k][ty * 8];
      *(float4*)&a[4] = *(const float4*)&As[k][ty * 8 + 4];
      *(float4*)&b[0] = *(const float4*)&Bs[k][tx * 4];
#pragma unroll
      for (int i = 0; i < 8; ++i)
#pragma unroll
        for (int j = 0; j < 4; ++j) acc[i][j] += a[i] * b[j];
    }
    __syncthreads();
  }

#pragma unroll
  for (int i = 0; i < 8; ++i) {
    int gr = row0 + ty * 8 + i;
    if (gr >= M) break;
#pragma unroll
    for (int j = 0; j < 4; ++j) {
      int gc = col0 + tx * 4 + j;
      if (gc >= N) continue;
      float v = acc[i][j];
      size_t off = (size_t)gr * ldC + gc;
      if (EPI == 1) v = fast_tanh(v + bias[gc]);
      if (EPI == 2) v = fast_sigmoid(v + bias[gc]);
      ((float*)Cv)[off] = v;
    }
  }
}

// ---------- launch ----------
static inline int cdiv(ll a, ll b) { return (int)((a + b - 1) / b); }

extern "C" void kernel_launch(void* const* d_in, const int* in_sizes, int n_in,
                              void* d_out, int out_size, void* d_ws, size_t ws_size,
                              hipStream_t stream) {
  const float* x  = (const float*)d_in[0];
  const void*  ei = d_in[1];
  const float* W1 = (const float*)d_in[2];
  const float* b1 = (const float*)d_in[3];
  const float* W2 = (const float*)d_in[4];
  const float* b2 = (const float*)d_in[5];
  const float* W3 = (const float*)d_in[6];
  const float* b3 = (const float*)d_in[7];
  const float* Wc = (const float*)d_in[8];
  const float* bc = (const float*)d_in[9];

  const int Nn = in_sizes[0] / 256;  // 100000
  const ll  E  = in_sizes[1] / 2;    // 400000

  // ===== d_ws (256.0 MB, proven): h1 bf16 [N,1024] | q3 fp32 [N,128] =====
  u16*   h1 = (u16*)d_ws;
  float* q3 = (float*)((char*)d_ws + (size_t)Nn * 1024 * 2);

  // ===== d_out scratch (22.8M floats), liveness-scheduled =====
  // [0,3N): deg|isd|invd (invd live through L3 gather; dead before classifier)
  // [3N, ~1.73M): rowp|cursor|colx|wgt|part|offs|Wt-bf16  (dead after last MFMA / L3 gather)
  // stA @1.8M (12.8M fl): L1 Sx-bf16 / L2 q_c fp32   (dead before L3 gather)
  // stB @14.6M (6.4M fl): L2 h2_c bf16               (dead before L3 gather)
  // final: outf [0,100N) | hout [100N, 228N)
  float* ob     = (float*)d_out;
  float* deg    = ob;
  float* isd    = ob + Nn;
  float* invd   = ob + 2 * (size_t)Nn;
  int*   rowp   = (int*)(ob + 3 * (size_t)Nn);          // Nn+1
  int*   cursor = (int*)(ob + 4 * (size_t)Nn + 4);      // Nn
  int*   colx   = (int*)(ob + 5 * (size_t)Nn + 8);      // E
  float* wgt    = ob + 5 * (size_t)Nn + 8 + E;          // E
  int*   part   = (int*)(ob + 5 * (size_t)Nn + 8 + 2 * E);   // 128
  int*   offs   = part + 128;                                 // 128
  u16*   W1t    = (u16*)(offs + 128);                   // [1024][256]
  u16*   W2t    = W1t + 1024 * 256;                     // [512][1024]
  u16*   W3t    = W2t + 512 * 1024;                     // [128][512]
  float* stA    = ob + 1800000;                         // 12.8M floats
  u16*   stB    = (u16*)(ob + 14600000);                // 12.8M u16
  float* outf   = ob;                                   // [N,100]
  float* hout   = ob + (size_t)Nn * 100;                // [N,128]

  const int T = 256;
  const int GY = cdiv(Nn, 128);
  const int SB = cdiv(Nn, 1024);  // scan blocks (98)

  // ---- degrees + CSR + weight conversion ----
  k_init<<<cdiv(Nn, T), T, 0, stream>>>(deg, cursor, Nn);
  k_edge_deg<<<cdiv(E, T), T, 0, stream>>>(ei, E, deg);
  k_fin_deg<<<cdiv(Nn, T), T, 0, stream>>>(deg, isd, invd, Nn);
  k_scan1<<<SB, 1024, 0, stream>>>(deg, rowp, part, Nn);
  k_scan2<<<1, 128, 0, stream>>>(part, offs, SB);
  k_scan3<<<SB, 1024, 0, stream>>>(rowp, offs, Nn);
  k_fill<<<cdiv(E, T), T, 0, stream>>>(ei, E, rowp, cursor, colx, wgt, isd);
  k_wt<<<cdiv(256 * 1024, T), T, 0, stream>>>(W1, W1t, 256, 1024);
  k_wt<<<cdiv(1024 * 512, T), T, 0, stream>>>(W2, W2t, 1024, 512);
  k_wt<<<cdiv(512 * 128, T), T, 0, stream>>>(W3, W3t, 512, 128);

  // ---- layer 1: Sx = S x (bf16), h1 = tanh(Sx @ W1 + b1) (bf16, MFMA) ----
  {
    ll t4 = (ll)Nn * 64;  // F=256
    k_gather<0, 1><<<cdiv(t4, T), T, 0, stream>>>(rowp, colx, wgt, x, 256, invd,
                                                  nullptr, stA, Nn, 6);
    dim3 g(1024 / 128, GY);
    k_mfma<0, 1, 1><<<g, T, 0, stream>>>((const u16*)stA, 256, W1t, 256, b1,
                                         h1, 1024, Nn, 256);
  }

  // ---- layer 2 (4 col-chunks of 128) fused with layer-3 GEMM:
  //      q_c = h1@W2[:,c]; h2_c = tanh(S q_c + b2_c) bf16; q3 (+)= h2_c @ W3[c,:] ----
  for (int c = 0; c < 4; ++c) {
    const int c0 = c * 128;
    {
      dim3 g(1, GY);
      k_mfma<0, 0, 0><<<g, T, 0, stream>>>(h1, 1024, W2t + (size_t)c0 * 1024, 1024,
                                           nullptr, stA, 128, Nn, 1024);
    }
    ll t4 = (ll)Nn * 32;  // F=128
    k_gather<1, 1><<<cdiv(t4, T), T, 0, stream>>>(rowp, colx, wgt, stA, 128, invd,
                                                  b2 + c0, stB, Nn, 5);
    {
      dim3 g(1, GY);
      if (c == 0)
        k_mfma<0, 0, 0><<<g, T, 0, stream>>>(stB, 128, W3t + c0, 512,
                                             nullptr, q3, 128, Nn, 128);
      else
        k_mfma<1, 0, 0><<<g, T, 0, stream>>>(stB, 128, W3t + c0, 512,
                                             nullptr, q3, 128, Nn, 128);
    }
  }

  // ---- layer 3 aggregation: h3 = tanh(S q3 + b3) -> hout (fp32) ----
  {
    ll t4 = (ll)Nn * 32;
    k_gather<1, 0><<<cdiv(t4, T), T, 0, stream>>>(rowp, colx, wgt, q3, 128, invd,
                                                  b3, hout, Nn, 5);
  }

  // ---- classifier: out = sigmoid(h3 @ Wc + bc) (fp32 VALU, N=100 tail) ----
  {
    dim3 g(cdiv(100, 64), GY);
    k_gemm<0, 0, 2, 0><<<g, T, 0, stream>>>(hout, 128, Wc, 100, bc, outf, 100, Nn, 100, 128);
  }
}